// Round 2
// baseline (239.822 us; speedup 1.0000x reference)
//
#include <hip/hip_runtime.h>

#define NB 256
#define NT 1024
#define NL 64

typedef __fp16 h2v __attribute__((ext_vector_type(2)));

__device__ __forceinline__ float rfl_f(float v) {
  return __builtin_bit_cast(float, __builtin_amdgcn_readfirstlane(__builtin_bit_cast(int, v)));
}

// DPP self-permute: result[l] = v[l ^ m] within a 16-lane row, for the xor-type
// ctrl codes used below (row_mirror=^15, row_half_mirror=^7, quad_perm ^3, ^1).
#define DPPI(V, C) __builtin_amdgcn_update_dpp(V, V, C, 0xF, 0xF, false)

// Expand t[0] (base mask 0) into t[0..15] covering base masks
// m_seq = {0,15,7,8, 3,12,4,11, 1,14,6,9,2,13,5,10} (generation order).
#define TREE_GEN(t)                                                           \
  t[1] = DPPI(t[0], 0x140); /* ^15 */                                         \
  t[2] = DPPI(t[0], 0x141); /* ^7  */                                         \
  t[3] = DPPI(t[1], 0x141); /* ^8  */                                         \
  _Pragma("unroll")                                                           \
  for (int k_ = 0; k_ < 4; k_++) t[4 + k_] = DPPI(t[k_], 0x1B); /* ^3 */      \
  _Pragma("unroll")                                                           \
  for (int k_ = 0; k_ < 8; k_++) t[8 + k_] = DPPI(t[k_], 0xB1); /* ^1 */

// One CRF step, all-register broadcast (no LDS storage, no permlane_swap).
//
// Gather: lane l needs all 64 w values as 32 packed f16 pairs.
//   quadrant gather: a16 = w[l^16], a32 = w[l^32], a48 = w[l^48] via three
//   INDEPENDENT ds_bpermute (latencies overlap; semantics certain).
//   With q = l>>4, b = l&15:  (w, a16) = (w[b+16q], w[b+16(q^1)]),
//                             (a32, a48) = (w[b+16(q^2)], w[b+16(q^3)]).
//   Two packed roots -> two DPP trees over masks {15,7,3,1} give all 16
//   in-row masks; per-lane ordering (q, b, m_seq) is compensated in the Rh
//   load order at setup. A-tree only needs a16, so its 16 fdot2 run while
//   a32/a48 are still in flight.
// Renorm: K = 2^(115-e8) from lane0's f32 exponent (uniform, off-chain);
// identical arithmetic to the verified round-0 scheme.
#define CRF_STEP(EF)                                                          \
  do {                                                                        \
    int wi = __builtin_bit_cast(int, w);                                      \
    int a16 = __builtin_amdgcn_ds_bpermute(adr16, wi);                        \
    int a32 = __builtin_amdgcn_ds_bpermute(adr32, wi);                        \
    int a48 = __builtin_amdgcn_ds_bpermute(adr48, wi);                        \
    int e8 = (__builtin_amdgcn_readfirstlane(wi) >> 23) & 0xff;               \
    float K = __builtin_bit_cast(float, (242 - e8) << 23);                    \
    float KE = K * (EF);                                                      \
    e2 += e8 - 115;                                                           \
    float s0 = 0.f, s1 = 0.f, s2 = 0.f, s3 = 0.f;                             \
    int tA[16], tB[16];                                                       \
    tA[0] = __builtin_bit_cast(int, __builtin_amdgcn_cvt_pkrtz(               \
                w, __builtin_bit_cast(float, a16)));                          \
    TREE_GEN(tA)                                                              \
    _Pragma("unroll")                                                         \
    for (int k = 0; k < 16; k += 2) {                                         \
      s0 = __builtin_amdgcn_fdot2(__builtin_bit_cast(h2v, tA[k]), Rh[k], s0, false);       \
      s1 = __builtin_amdgcn_fdot2(__builtin_bit_cast(h2v, tA[k + 1]), Rh[k + 1], s1, false); \
    }                                                                         \
    tB[0] = __builtin_bit_cast(int, __builtin_amdgcn_cvt_pkrtz(               \
                __builtin_bit_cast(float, a32), __builtin_bit_cast(float, a48))); \
    TREE_GEN(tB)                                                              \
    _Pragma("unroll")                                                         \
    for (int k = 0; k < 16; k += 2) {                                         \
      s2 = __builtin_amdgcn_fdot2(__builtin_bit_cast(h2v, tB[k]), Rh[16 + k], s2, false);     \
      s3 = __builtin_amdgcn_fdot2(__builtin_bit_cast(h2v, tB[k + 1]), Rh[17 + k], s3, false); \
    }                                                                         \
    w = ((s0 + s1) + (s2 + s3)) * KE;                                         \
  } while (0)

// Blocks 0..255: forward chains. 256..511: backward chains. 512..767: gold path
// (hides under the fb waves co-resident on the same CUs).
// __launch_bounds__(64, 1): only ~3 waves/CU exist; lift the default VGPR cap
// so Rh + DPP trees stay in arch VGPRs (round-1 regression: VGPR_Count=36 ->
// AGPR shuffling inside the serial loop).
__global__ __launch_bounds__(64, 1) void fb_kernel(const float* __restrict__ scores,
                                                   const int* __restrict__ targets,
                                                   const float* __restrict__ start,
                                                   const float* __restrict__ Tm,
                                                   const float* __restrict__ endv,
                                                   float* __restrict__ wsA,
                                                   float* __restrict__ wsB,
                                                   float* __restrict__ wsG) {
  const int lane = threadIdx.x;
  const int bb = blockIdx.x;

  if (bb >= 2 * NB) {  // ---- gold path: one wave per batch ----
    const int b = bb - 2 * NB;
    const int* tg = targets + b * NT;
    const float* sc = scores + (size_t)b * NT * NL;
    float acc = 0.f;
    for (int t = lane; t < NT; t += 64) {
      int c = tg[t];
      acc += sc[t * NL + c];
      if (t > 0) acc += Tm[c * NL + tg[t - 1]];  // T_mat[cur, prev]
    }
#pragma unroll
    for (int off = 32; off > 0; off >>= 1) acc += __shfl_xor(acc, off, 64);
    if (lane == 0) wsG[b] = acc + start[tg[0]] + endv[tg[NT - 1]];
    return;
  }

  const bool bwd = bb >= NB;
  const int b = bwd ? bb - NB : bb;
  const float* sc = scores + (size_t)b * NT * NL;
  const float LN2 = 0.69314718055994530942f;

  const int adr16 = (lane ^ 16) << 2;  // ds_bpermute byte addresses (loop-invariant)
  const int adr32 = (lane ^ 32) << 2;
  const int adr48 = (lane ^ 48) << 2;

  // Per-lane gather ordering: tree slot i holds base index (lane&15) ^ m_seq[i];
  // A-tree halves are quadrants (q, q^1), B-tree halves (q^2, q^3), q = lane>>4.
  constexpr int m_seq[16] = {0, 15, 7, 8, 3, 12, 4, 11, 1, 14, 6, 9, 2, 13, 5, 10};
  const int q = lane >> 4;
  const int bidx = lane & 15;

  // f16 transition table in gather order:
  //  fwd r(p) = exp(T[lane][p])   (Tb = Tm + lane*NL, str = 1)
  //  bwd r(p) = exp(T[p][lane])   (Tb = Tm + lane,    str = NL)
  const float* Tb = bwd ? (Tm + lane) : (Tm + lane * NL);
  const int str = bwd ? NL : 1;
  h2v Rh[32];
#pragma unroll
  for (int i = 0; i < 16; i++) {
    int bm = bidx ^ m_seq[i];
    Rh[i] = __builtin_amdgcn_cvt_pkrtz(__expf(Tb[(bm + 16 * q) * str]),
                                       __expf(Tb[(bm + 16 * (q ^ 1)) * str]));
    Rh[16 + i] = __builtin_amdgcn_cvt_pkrtz(__expf(Tb[(bm + 16 * (q ^ 2)) * str]),
                                            __expf(Tb[(bm + 16 * (q ^ 3)) * str]));
  }

  if (!bwd) {
    float a0 = start[lane] + sc[lane];  // alpha_0
    float m0 = rfl_f(a0);
    float w = __expf(a0 - m0) * 16.f;   // keep w_0 in f16-normal range
    int e2 = -4;

    float buf[4];
#pragma unroll
    for (int k = 0; k < 4; k++) buf[k] = sc[(1 + k) * NL + lane];

    for (int i = 0; i < 128; i++) {  // 512 steps: t = 1..512
      float nb4[4];
      int tb = 5 + 4 * i;  // prefetch (max t=516 < 1024)
#pragma unroll
      for (int k = 0; k < 4; k++) nb4[k] = sc[(tb + k) * NL + lane];
      float Ev[4];
#pragma unroll
      for (int k = 0; k < 4; k++) Ev[k] = __expf(buf[k]);  // off critical chain
      CRF_STEP(Ev[0]);
      CRF_STEP(Ev[1]);
      CRF_STEP(Ev[2]);
      CRF_STEP(Ev[3]);
#pragma unroll
      for (int k = 0; k < 4; k++) buf[k] = nb4[k];
    }
    wsA[lane * NB + b] = m0 + (float)e2 * LN2 + __logf(w);  // alpha_512 (transposed)
  } else {
    float a0 = endv[lane] + sc[(NT - 1) * NL + lane];
    float m0 = rfl_f(a0);
    float w = __expf(a0 - m0) * 16.f;
    int e2 = -4;

    float buf[4];
#pragma unroll
    for (int k = 0; k < 4; k++) buf[k] = sc[(1022 - k) * NL + lane];

    for (int i = 0; i < 127; i++) {  // 508 steps: te = 1022..515
      float nb4[4];
      int tb = 1018 - 4 * i;  // prefetch (min 511 >= 0)
#pragma unroll
      for (int k = 0; k < 4; k++) nb4[k] = sc[(tb - k) * NL + lane];
      float Ev[4];
#pragma unroll
      for (int k = 0; k < 4; k++) Ev[k] = __expf(buf[k]);
      CRF_STEP(Ev[0]);
      CRF_STEP(Ev[1]);
      CRF_STEP(Ev[2]);
      CRF_STEP(Ev[3]);
#pragma unroll
      for (int k = 0; k < 4; k++) buf[k] = nb4[k];
    }
    CRF_STEP(__expf(sc[514 * NL + lane]));
    CRF_STEP(__expf(sc[513 * NL + lane]));
    CRF_STEP(1.0f);  // final matvec-only step -> beta_512
    wsB[lane * NB + b] = m0 + (float)e2 * LN2 + __logf(w);  // beta_512 (transposed)
  }
}

// thread b handles batch b: lse over 64 states (coalesced via transposed ws layout),
// subtract gold, block-reduce mean.
__global__ __launch_bounds__(256) void combine_kernel(const float* __restrict__ wsA,
                                                      const float* __restrict__ wsB,
                                                      const float* __restrict__ wsG,
                                                      float* __restrict__ out) {
  const int b = threadIdx.x;
  float m = -INFINITY;
#pragma unroll
  for (int j = 0; j < NL; j++) m = fmaxf(m, wsA[j * NB + b] + wsB[j * NB + b]);
  float s = 0.f;
#pragma unroll
  for (int j = 0; j < NL; j++) s += __expf(wsA[j * NB + b] + wsB[j * NB + b] - m);
  float loss = (m + __logf(s)) - wsG[b];
#pragma unroll
  for (int off = 32; off > 0; off >>= 1) loss += __shfl_xor(loss, off, 64);
  __shared__ float red[4];
  if ((b & 63) == 0) red[b >> 6] = loss;
  __syncthreads();
  if (b == 0) out[0] = (red[0] + red[1] + red[2] + red[3]) * (1.0f / NB);
}

extern "C" void kernel_launch(void* const* d_in, const int* in_sizes, int n_in,
                              void* d_out, int out_size, void* d_ws, size_t ws_size,
                              hipStream_t stream) {
  const float* scores = (const float*)d_in[0];
  const int* targets = (const int*)d_in[1];
  const float* start = (const float*)d_in[2];
  const float* Tm = (const float*)d_in[3];
  const float* endv = (const float*)d_in[4];
  float* out = (float*)d_out;

  float* wsA = (float*)d_ws;       // [NL*NB] alpha_512, transposed [state][batch]
  float* wsB = wsA + NB * NL;      // [NL*NB] beta_512, transposed
  float* wsG = wsB + NB * NL;      // [NB] gold path scores

  fb_kernel<<<3 * NB, 64, 0, stream>>>(scores, targets, start, Tm, endv, wsA, wsB, wsG);
  combine_kernel<<<1, 256, 0, stream>>>(wsA, wsB, wsG, out);
}

// Round 3
// 236.516 us; speedup vs baseline: 1.0140x; 1.0140x over previous
//
#include <hip/hip_runtime.h>

#define NB 256
#define NT 1024
#define NL 64

typedef __fp16 h2v __attribute__((ext_vector_type(2)));

__device__ __forceinline__ float rfl_f(float v) {
  return __builtin_bit_cast(float, __builtin_amdgcn_readfirstlane(__builtin_bit_cast(int, v)));
}

// DPP self-permute: result[l] = v[l ^ m] within a 16-lane row, for the xor-type
// ctrl codes used below (row_mirror=^15, row_half_mirror=^7, quad_perm ^3, ^1).
// HW-verified by round-2 absmax=0.
#define DPPI(V, C) __builtin_amdgcn_update_dpp(V, V, C, 0xF, 0xF, false)

#define FD(S, T, R) \
  S = __builtin_amdgcn_fdot2(__builtin_bit_cast(h2v, T), Rh[R], S, false)

// One CRF step, all-register broadcast. SAME MATH as round 2 (verified), but
// the butterfly tree lives in NAMED SCALARS, not local arrays: rule #20 —
// the round-1/2 local arrays (P[32], tA[16]) were demoted to scratch
// (VGPR_Count collapsed 60->36, ~550 stall cy/step on scratch round trips).
//
// Gather: a16/a32/a48 = w[l^16/32/48] via 3 independent ds_bpermute, then two
// packed DPP trees over masks {15,7,3,1}; per-lane ordering (q=l>>4, b=l&15,
// m_seq) is compensated in the Rh load order at setup.
// Renorm: K = 2^(115-e8) from lane0's f32 exponent (uniform, off-chain).
#define CRF_STEP(EF)                                                          \
  do {                                                                        \
    int wi = __builtin_bit_cast(int, w);                                      \
    int a16 = __builtin_amdgcn_ds_bpermute(adr16, wi);                        \
    int a32 = __builtin_amdgcn_ds_bpermute(adr32, wi);                        \
    int a48 = __builtin_amdgcn_ds_bpermute(adr48, wi);                        \
    int e8 = (__builtin_amdgcn_readfirstlane(wi) >> 23) & 0xff;               \
    float K = __builtin_bit_cast(float, (242 - e8) << 23);                    \
    float KE = K * (EF);                                                      \
    e2 += e8 - 115;                                                           \
    float s0 = 0.f, s1 = 0.f, s2 = 0.f, s3 = 0.f;                             \
    int tA0 = __builtin_bit_cast(int, __builtin_amdgcn_cvt_pkrtz(             \
                  w, __builtin_bit_cast(float, a16)));                        \
    int tA1 = DPPI(tA0, 0x140);                                               \
    int tA2 = DPPI(tA0, 0x141);                                               \
    int tA3 = DPPI(tA1, 0x141);                                               \
    int tA4 = DPPI(tA0, 0x1B);                                                \
    int tA5 = DPPI(tA1, 0x1B);                                                \
    int tA6 = DPPI(tA2, 0x1B);                                                \
    int tA7 = DPPI(tA3, 0x1B);                                                \
    int tA8 = DPPI(tA0, 0xB1);                                                \
    int tA9 = DPPI(tA1, 0xB1);                                                \
    int tA10 = DPPI(tA2, 0xB1);                                               \
    int tA11 = DPPI(tA3, 0xB1);                                               \
    int tA12 = DPPI(tA4, 0xB1);                                               \
    int tA13 = DPPI(tA5, 0xB1);                                               \
    int tA14 = DPPI(tA6, 0xB1);                                               \
    int tA15 = DPPI(tA7, 0xB1);                                               \
    FD(s0, tA0, 0);  FD(s1, tA1, 1);  FD(s0, tA2, 2);  FD(s1, tA3, 3);        \
    FD(s0, tA4, 4);  FD(s1, tA5, 5);  FD(s0, tA6, 6);  FD(s1, tA7, 7);        \
    FD(s0, tA8, 8);  FD(s1, tA9, 9);  FD(s0, tA10, 10); FD(s1, tA11, 11);     \
    FD(s0, tA12, 12); FD(s1, tA13, 13); FD(s0, tA14, 14); FD(s1, tA15, 15);   \
    int tB0 = __builtin_bit_cast(int, __builtin_amdgcn_cvt_pkrtz(             \
                  __builtin_bit_cast(float, a32),                             \
                  __builtin_bit_cast(float, a48)));                           \
    int tB1 = DPPI(tB0, 0x140);                                               \
    int tB2 = DPPI(tB0, 0x141);                                               \
    int tB3 = DPPI(tB1, 0x141);                                               \
    int tB4 = DPPI(tB0, 0x1B);                                                \
    int tB5 = DPPI(tB1, 0x1B);                                                \
    int tB6 = DPPI(tB2, 0x1B);                                                \
    int tB7 = DPPI(tB3, 0x1B);                                                \
    int tB8 = DPPI(tB0, 0xB1);                                                \
    int tB9 = DPPI(tB1, 0xB1);                                                \
    int tB10 = DPPI(tB2, 0xB1);                                               \
    int tB11 = DPPI(tB3, 0xB1);                                               \
    int tB12 = DPPI(tB4, 0xB1);                                               \
    int tB13 = DPPI(tB5, 0xB1);                                               \
    int tB14 = DPPI(tB6, 0xB1);                                               \
    int tB15 = DPPI(tB7, 0xB1);                                               \
    FD(s2, tB0, 16); FD(s3, tB1, 17); FD(s2, tB2, 18); FD(s3, tB3, 19);       \
    FD(s2, tB4, 20); FD(s3, tB5, 21); FD(s2, tB6, 22); FD(s3, tB7, 23);       \
    FD(s2, tB8, 24); FD(s3, tB9, 25); FD(s2, tB10, 26); FD(s3, tB11, 27);     \
    FD(s2, tB12, 28); FD(s3, tB13, 29); FD(s2, tB14, 30); FD(s3, tB15, 31);   \
    w = ((s0 + s1) + (s2 + s3)) * KE;                                         \
  } while (0)

// Blocks 0..255: forward chains. 256..511: backward chains. 512..767: gold path.
__global__ __launch_bounds__(64, 1) void fb_kernel(const float* __restrict__ scores,
                                                   const int* __restrict__ targets,
                                                   const float* __restrict__ start,
                                                   const float* __restrict__ Tm,
                                                   const float* __restrict__ endv,
                                                   float* __restrict__ wsA,
                                                   float* __restrict__ wsB,
                                                   float* __restrict__ wsG) {
  const int lane = threadIdx.x;
  const int bb = blockIdx.x;

  if (bb >= 2 * NB) {  // ---- gold path: one wave per batch ----
    const int b = bb - 2 * NB;
    const int* tg = targets + b * NT;
    const float* sc = scores + (size_t)b * NT * NL;
    float acc = 0.f;
    for (int t = lane; t < NT; t += 64) {
      int c = tg[t];
      acc += sc[t * NL + c];
      if (t > 0) acc += Tm[c * NL + tg[t - 1]];  // T_mat[cur, prev]
    }
#pragma unroll
    for (int off = 32; off > 0; off >>= 1) acc += __shfl_xor(acc, off, 64);
    if (lane == 0) wsG[b] = acc + start[tg[0]] + endv[tg[NT - 1]];
    return;
  }

  const bool bwd = bb >= NB;
  const int b = bwd ? bb - NB : bb;
  const float* sc = scores + (size_t)b * NT * NL;
  const float LN2 = 0.69314718055994530942f;

  const int adr16 = (lane ^ 16) << 2;  // ds_bpermute byte addresses (loop-invariant)
  const int adr32 = (lane ^ 32) << 2;
  const int adr48 = (lane ^ 48) << 2;

  // Per-lane gather ordering: tree slot i holds base index (lane&15) ^ m_seq[i];
  // A-tree halves are quadrants (q, q^1), B-tree halves (q^2, q^3), q = lane>>4.
  constexpr int m_seq[16] = {0, 15, 7, 8, 3, 12, 4, 11, 1, 14, 6, 9, 2, 13, 5, 10};
  const int q = lane >> 4;
  const int bidx = lane & 15;

  // f16 transition table in gather order (verified round 2):
  //  fwd r(p) = exp(T[lane][p])   (Tb = Tm + lane*NL, str = 1)
  //  bwd r(p) = exp(T[p][lane])   (Tb = Tm + lane,    str = NL)
  const float* Tb = bwd ? (Tm + lane) : (Tm + lane * NL);
  const int str = bwd ? NL : 1;
  h2v Rh[32];
#pragma unroll
  for (int i = 0; i < 16; i++) {
    int bm = bidx ^ m_seq[i];
    Rh[i] = __builtin_amdgcn_cvt_pkrtz(__expf(Tb[(bm + 16 * q) * str]),
                                       __expf(Tb[(bm + 16 * (q ^ 1)) * str]));
    Rh[16 + i] = __builtin_amdgcn_cvt_pkrtz(__expf(Tb[(bm + 16 * (q ^ 2)) * str]),
                                            __expf(Tb[(bm + 16 * (q ^ 3)) * str]));
  }

  if (!bwd) {
    float a0 = start[lane] + sc[lane];  // alpha_0
    float m0 = rfl_f(a0);
    float w = __expf(a0 - m0) * 16.f;   // keep w_0 in f16-normal range
    int e2 = -4;

    float buf[4];
#pragma unroll
    for (int k = 0; k < 4; k++) buf[k] = sc[(1 + k) * NL + lane];

    for (int i = 0; i < 128; i++) {  // 512 steps: t = 1..512
      float nb4[4];
      int tb = 5 + 4 * i;  // prefetch (max t=516 < 1024)
#pragma unroll
      for (int k = 0; k < 4; k++) nb4[k] = sc[(tb + k) * NL + lane];
      float Ev[4];
#pragma unroll
      for (int k = 0; k < 4; k++) Ev[k] = __expf(buf[k]);  // off critical chain
      CRF_STEP(Ev[0]);
      CRF_STEP(Ev[1]);
      CRF_STEP(Ev[2]);
      CRF_STEP(Ev[3]);
#pragma unroll
      for (int k = 0; k < 4; k++) buf[k] = nb4[k];
    }
    wsA[b * NL + lane] = m0 + (float)e2 * LN2 + __logf(w);  // alpha_512 (coalesced)
  } else {
    float a0 = endv[lane] + sc[(NT - 1) * NL + lane];
    float m0 = rfl_f(a0);
    float w = __expf(a0 - m0) * 16.f;
    int e2 = -4;

    float buf[4];
#pragma unroll
    for (int k = 0; k < 4; k++) buf[k] = sc[(1022 - k) * NL + lane];

    for (int i = 0; i < 127; i++) {  // 508 steps: te = 1022..515
      float nb4[4];
      int tb = 1018 - 4 * i;  // prefetch (min 511 >= 0)
#pragma unroll
      for (int k = 0; k < 4; k++) nb4[k] = sc[(tb - k) * NL + lane];
      float Ev[4];
#pragma unroll
      for (int k = 0; k < 4; k++) Ev[k] = __expf(buf[k]);
      CRF_STEP(Ev[0]);
      CRF_STEP(Ev[1]);
      CRF_STEP(Ev[2]);
      CRF_STEP(Ev[3]);
#pragma unroll
      for (int k = 0; k < 4; k++) buf[k] = nb4[k];
    }
    CRF_STEP(__expf(sc[514 * NL + lane]));
    CRF_STEP(__expf(sc[513 * NL + lane]));
    CRF_STEP(1.0f);  // final matvec-only step -> beta_512
    wsB[b * NL + lane] = m0 + (float)e2 * LN2 + __logf(w);  // beta_512 (coalesced)
  }
}

// Parallel combine: 16 waves; wave wv lse-reduces batches {wv, wv+16, ...}
// (coalesced 256B loads per batch via the [b][state] ws layout), then the
// round-0 final reduction is replayed from LDS losses[256].
// Replaces the 1-block serial combine that was ~80 us (dur_us - fb_dur was a
// constant 82-83 us across rounds 0-2 while fb varied).
__global__ __launch_bounds__(1024) void combine_kernel(const float* __restrict__ wsA,
                                                       const float* __restrict__ wsB,
                                                       const float* __restrict__ wsG,
                                                       float* __restrict__ out) {
  const int tid = threadIdx.x;
  const int lane = tid & 63;
  const int wv = tid >> 6;  // 0..15
  __shared__ float losses[NB];
  __shared__ float red[4];

  for (int b = wv; b < NB; b += 16) {
    float v = wsA[b * NL + lane] + wsB[b * NL + lane];
    float m = v;
#pragma unroll
    for (int off = 32; off > 0; off >>= 1) m = fmaxf(m, __shfl_xor(m, off, 64));
    float s = __expf(v - m);
#pragma unroll
    for (int off = 32; off > 0; off >>= 1) s += __shfl_xor(s, off, 64);
    if (lane == 0) losses[b] = (m + __logf(s)) - wsG[b];
  }
  __syncthreads();

  if (tid < NB) {
    float loss = losses[tid];
#pragma unroll
    for (int off = 32; off > 0; off >>= 1) loss += __shfl_xor(loss, off, 64);
    if ((tid & 63) == 0) red[tid >> 6] = loss;
  }
  __syncthreads();
  if (tid == 0) out[0] = (red[0] + red[1] + red[2] + red[3]) * (1.0f / NB);
}

extern "C" void kernel_launch(void* const* d_in, const int* in_sizes, int n_in,
                              void* d_out, int out_size, void* d_ws, size_t ws_size,
                              hipStream_t stream) {
  const float* scores = (const float*)d_in[0];
  const int* targets = (const int*)d_in[1];
  const float* start = (const float*)d_in[2];
  const float* Tm = (const float*)d_in[3];
  const float* endv = (const float*)d_in[4];
  float* out = (float*)d_out;

  float* wsA = (float*)d_ws;       // [NB*NL] alpha_512, [batch][state]
  float* wsB = wsA + NB * NL;      // [NB*NL] beta_512, [batch][state]
  float* wsG = wsB + NB * NL;      // [NB] gold path scores

  fb_kernel<<<3 * NB, 64, 0, stream>>>(scores, targets, start, Tm, endv, wsA, wsB, wsG);
  combine_kernel<<<1, 1024, 0, stream>>>(wsA, wsB, wsG, out);
}